// Round 17
// baseline (22.404 us; speedup 1.0000x reference)
//
#include <hip/hip_runtime.h>
#include <stdint.h>

// Problem constants: B,D,K,CI,CO,L,NB,P,S = 4,32,8,2,2,4096,15,7,8
constexpr int Bc  = 4;
constexpr int Dc  = 32;
constexpr int Kc  = 8;
constexpr int CIc = 2;
constexpr int COc = 2;
constexpr int Lc  = 4096;
constexpr int NBc = 15;
constexpr int Sc  = 8;

constexpr int NTHREADS = 256;
constexpr int JT       = 4;                   // outputs per thread per co
constexpr int TILE     = NTHREADS * JT;       // 1024 = quarter row
constexpr int NQ       = Lc / TILE;           // 4 quarters per row
constexpr int WELEMS   = COc * CIc * Sc * NBc;   // 480

typedef float f32x4 __attribute__((ext_vector_type(4)));
typedef const __attribute__((address_space(1))) float* gas1_t;  // global
typedef __attribute__((address_space(3))) float* las3_t;        // LDS

// seg(l) = min(l/499, 7)
__device__ __forceinline__ int seg_of(int l) {
    int s = l / 499;
    return s > 7 ? 7 : s;
}

__global__ __launch_bounds__(NTHREADS) void cde_bcr_kernel(
    const float* __restrict__ x,     // [B][D][K][CI][L]
    const float* __restrict__ w,     // [D][K][CO][CI][S][1][NB]
    const float* __restrict__ bias,  // [D][K][CO][S][1]
    float* __restrict__ out)         // [B][D][K][CO][L]
{
    // quarter-row staged: xs[i][8+m] = x[i][qbase+m], m in [0,1024).
    // LDS 10.4 KB -> 8 blocks/CU (wave-capped) -> 2048 resident; grid 4096 -> 2 GENERATIONS:
    // gen-2 DMA reads stream while gen-1 computes/writes (grid-level pipelining).
    __shared__ __align__(16) float xs[CIc][TILE + 16];
    __shared__ __align__(16) float wl[COc * CIc * Sc][16]; // row=(o*CI+i)*S+s
    __shared__ float bl[COc * Sc];

    const int tid   = threadIdx.x;
    const int lane  = tid & 63;
    const int wv    = tid >> 6;              // wave 0..3
    const int row   = blockIdx.x >> 2;       // ((b*D + d)*K + k)
    const int qbase = (blockIdx.x & 3) * TILE;
    const int dk    = row % (Dc * Kc);

    // ---- fire-and-forget DMA: quarter row, 2 gload_lds_dwordx4 per wave ----
    // LDS dest wave-uniform base + lane*16 (m104); offsets 16B-aligned.
    const float* xrow = x + (size_t)row * CIc * Lc;
#pragma unroll
    for (int i = 0; i < CIc; ++i) {
        const float* g = xrow + (size_t)i * Lc + qbase + wv * 256 + lane * 4;
        __builtin_amdgcn_global_load_lds((gas1_t)g,
            (las3_t)&xs[i][8 + wv * 256], 16, 0, 0);
    }

    // ---- weights + bias (overlaps DMA) ----
    for (int t = tid; t < WELEMS; t += NTHREADS)
        wl[t / NBc][t % NBc] = w[(size_t)dk * WELEMS + t];
    if (tid < COc * Sc)
        bl[tid] = bias[(size_t)dk * (COc * Sc) + tid];

    __syncthreads();   // drains DMA + LDS writes

    const int low = tid * JT;                // offset within quarter
    const int gl0 = qbase + low;             // row-local l
    const int s0  = seg_of(gl0);
    const int s3  = seg_of(gl0 + JT - 1);

    // ---- window xa_i[m] = x[i][gl0-8+m], m in [0,20) ----
    float xa0[20], xa1[20];
    if (low >= 8 && low <= TILE - 12) {
        // interior: 5 ds_read_b128 per ci, 16B lane stride -> conflict-free
#pragma unroll
        for (int m = 0; m < 5; ++m) {
            *(f32x4*)&xa0[4 * m] = *(const f32x4*)&xs[0][low + 4 * m];
            *(f32x4*)&xa1[4 * m] = *(const f32x4*)&xs[1][low + 4 * m];
        }
    } else {
        // quarter-edge threads (tid 0,1,254,255): global, bounds-checked
        // (also covers row ends l<0 / l>=Lc -> 0)
#pragma unroll
        for (int m = 0; m < 20; ++m) {
            int l = gl0 - 8 + m;
            bool ok = (l >= 0 && l < Lc);
            xa0[m] = ok ? xrow[l] : 0.0f;
            xa1[m] = ok ? xrow[Lc + l] : 0.0f;
        }
    }

    float acc[COc][JT];
#pragma unroll
    for (int o = 0; o < COc; ++o)
#pragma unroll
        for (int j = 0; j < JT; ++j)
            acc[o][j] = bl[o * Sc + s0];

    // ---- main FMA block, uniform segment s0 ----
#pragma unroll
    for (int i = 0; i < CIc; ++i) {
        float wa[16], wb[16];
#pragma unroll
        for (int m = 0; m < 4; ++m) {
            *(f32x4*)&wa[4 * m] = *(const f32x4*)&wl[(0 * CIc + i) * Sc + s0][4 * m];
            *(f32x4*)&wb[4 * m] = *(const f32x4*)&wl[(1 * CIc + i) * Sc + s0][4 * m];
        }
#pragma unroll
        for (int f = 0; f < NBc; ++f) {
#pragma unroll
            for (int j = 0; j < JT; ++j) {
                float xv = (i == 0) ? xa0[j + f + 1] : xa1[j + f + 1];
                acc[0][j] = fmaf(wa[f], xv, acc[0][j]);
                acc[1][j] = fmaf(wb[f], xv, acc[1][j]);
            }
        }
    }

    // ---- fixup: segment-boundary threads (<=7 per row), all register indices static ----
    if (s3 != s0) {
        const int jstart = 499 * s3 - gl0;   // in [1, JT-1]
        const float b0 = bl[0 * Sc + s3];
        const float b1 = bl[1 * Sc + s3];
#pragma unroll
        for (int j = 0; j < JT; ++j) {
            if (j >= jstart) {
                float a0 = b0, a1 = b1;
#pragma unroll
                for (int i = 0; i < CIc; ++i) {
#pragma unroll
                    for (int f = 0; f < NBc; ++f) {
                        float xv = (i == 0) ? xa0[j + f + 1] : xa1[j + f + 1];
                        a0 = fmaf(wl[(0 * CIc + i) * Sc + s3][f], xv, a0);
                        a1 = fmaf(wl[(1 * CIc + i) * Sc + s3][f], xv, a1);
                    }
                }
                acc[0][j] = a0;
                acc[1][j] = a1;
            }
        }
    }

    // ---- store: 2 nontemporal dwordx4 (NT proven right: r13 plain stores -7.3us) ----
    float* ob = out + (size_t)row * COc * Lc + gl0;
    f32x4 v0 = { acc[0][0], acc[0][1], acc[0][2], acc[0][3] };
    f32x4 v1 = { acc[1][0], acc[1][1], acc[1][2], acc[1][3] };
    __builtin_nontemporal_store(v0, (f32x4*)(ob));
    __builtin_nontemporal_store(v1, (f32x4*)(ob + Lc));
}

extern "C" void kernel_launch(void* const* d_in, const int* in_sizes, int n_in,
                              void* d_out, int out_size, void* d_ws, size_t ws_size,
                              hipStream_t stream) {
    const float* x    = (const float*)d_in[0];
    const float* w    = (const float*)d_in[1];
    const float* bias = (const float*)d_in[2];
    float* out        = (float*)d_out;

    // 4096 blocks > 2048 resident -> 2 generations: gen-2 reads overlap gen-1 compute/write
    cde_bcr_kernel<<<dim3(Bc * Dc * Kc * NQ), NTHREADS, 0, stream>>>(x, w, bias, out);
}

// Round 18
// 18.738 us; speedup vs baseline: 1.1956x; 1.1956x over previous
//
#include <hip/hip_runtime.h>
#include <stdint.h>

// Problem constants: B,D,K,CI,CO,L,NB,P,S = 4,32,8,2,2,4096,15,7,8
constexpr int Bc  = 4;
constexpr int Dc  = 32;
constexpr int Kc  = 8;
constexpr int CIc = 2;
constexpr int COc = 2;
constexpr int Lc  = 4096;
constexpr int NBc = 15;
constexpr int Sc  = 8;

constexpr int NTHREADS = 256;
constexpr int JT       = 4;                  // outputs per thread per co per tile
constexpr int TILE     = NTHREADS * JT;      // 1024
constexpr int NTILES   = Lc / TILE;          // 4 tiles = whole row per block
constexpr int WELEMS   = COc * CIc * Sc * NBc;  // 480

typedef float f32x4 __attribute__((ext_vector_type(4)));
typedef const __attribute__((address_space(1))) float* gas1_t;  // global
typedef __attribute__((address_space(3))) float* las3_t;        // LDS

// seg(l) = min(l/499, 7)
__device__ __forceinline__ int seg_of(int l) {
    int s = l / 499;
    return s > 7 ? 7 : s;
}

__global__ __launch_bounds__(NTHREADS) void cde_bcr_kernel(
    const float* __restrict__ x,     // [B][D][K][CI][L]
    const float* __restrict__ w,     // [D][K][CO][CI][S][1][NB]
    const float* __restrict__ bias,  // [D][K][CO][S][1]
    float* __restrict__ out)         // [B][D][K][CO][L]
{
    // whole x row staged: xs[i][8 + l] = x[i][l]; halos [0,8) and [8+Lc,16+Lc) zeroed
    __shared__ __align__(16) float xs[CIc][Lc + 16];          // 32.9 KB -> 4 blocks/CU
    __shared__ __align__(16) float wl[COc * CIc * Sc][16];    // 2 KB
    __shared__ float bl[COc * Sc];

    const int tid  = threadIdx.x;
    const int lane = tid & 63;
    const int wid  = tid >> 6;
    const int bdk  = blockIdx.x;             // ((b*D + d)*K + k), 1024 blocks
    const int dk   = bdk % (Dc * Kc);

    // ---- fire-and-forget: whole row direct HBM->LDS, zero VGPR cost (m97 width=16) ----
    // LDS dest wave-uniform base + lane*16 (m104); all byte offsets 16B-aligned.
    const float* xrow = x + (size_t)bdk * CIc * Lc;
#pragma unroll
    for (int i = 0; i < CIc; ++i) {
#pragma unroll
        for (int q = 0; q < 4; ++q) {        // 4 sweeps x 1024 floats per ci
            const float* g = xrow + (size_t)i * Lc + q * 1024 + wid * 256 + lane * 4;
            float* lp = &xs[i][8 + q * 1024 + wid * 256];   // wave-uniform base
            __builtin_amdgcn_global_load_lds((gas1_t)g, (las3_t)lp, 16, 0, 0);
        }
    }

    // ---- weights + bias (regular staging, overlaps DMA) ----
    for (int t = tid; t < WELEMS; t += NTHREADS)
        wl[t / NBc][t % NBc] = w[(size_t)dk * WELEMS + t];
    if (tid < COc * Sc)
        bl[tid] = bias[(size_t)dk * (COc * Sc) + tid];

    // ---- zero halos (row ends pad with 0) ----
    if (tid < 2 * 16) {
        int i = tid >> 4, e = tid & 15;
        int idx = (e < 8) ? e : (Lc + e);    // [0,8) and [Lc+8, Lc+16)
        xs[i][idx] = 0.0f;
    }

    __syncthreads();   // drains DMA + LDS writes; blocks release staggered grid-wide

#pragma unroll
    for (int t = 0; t < NTILES; ++t) {
        const int gl0 = t * TILE + tid * JT;
        const int s0  = seg_of(gl0);
        const int s3  = seg_of(gl0 + JT - 1);

        // windows: xa_i[m] = x[i][gl0-8+m] = xs[i][gl0+m], m in [0,20)
        // ds_read_b128 at 16B lane stride: contiguous 1KB/wave -> conflict-free
        float xa0[20], xa1[20];
#pragma unroll
        for (int m = 0; m < 5; ++m) {
            *(f32x4*)&xa0[4 * m] = *(const f32x4*)&xs[0][gl0 + 4 * m];
            *(f32x4*)&xa1[4 * m] = *(const f32x4*)&xs[1][gl0 + 4 * m];
        }

        float acc[COc][JT];
#pragma unroll
        for (int o = 0; o < COc; ++o)
#pragma unroll
            for (int j = 0; j < JT; ++j)
                acc[o][j] = bl[o * Sc + s0];

#pragma unroll
        for (int i = 0; i < CIc; ++i) {
            float wa[16], wb[16];
#pragma unroll
            for (int m = 0; m < 4; ++m) {
                *(f32x4*)&wa[4 * m] = *(const f32x4*)&wl[(0 * CIc + i) * Sc + s0][4 * m];
                *(f32x4*)&wb[4 * m] = *(const f32x4*)&wl[(1 * CIc + i) * Sc + s0][4 * m];
            }
#pragma unroll
            for (int f = 0; f < NBc; ++f) {
#pragma unroll
                for (int j = 0; j < JT; ++j) {
                    float xv = (i == 0) ? xa0[j + f + 1] : xa1[j + f + 1];
                    acc[0][j] = fmaf(wa[f], xv, acc[0][j]);
                    acc[1][j] = fmaf(wb[f], xv, acc[1][j]);
                }
            }
        }

        // fixup: segment-boundary threads, all register indices static
        if (s3 != s0) {
            const int jstart = 499 * s3 - gl0;   // in [1, JT-1]
            const float b0 = bl[0 * Sc + s3];
            const float b1 = bl[1 * Sc + s3];
#pragma unroll
            for (int j = 0; j < JT; ++j) {
                if (j >= jstart) {
                    float a0 = b0, a1 = b1;
#pragma unroll
                    for (int i = 0; i < CIc; ++i) {
#pragma unroll
                        for (int f = 0; f < NBc; ++f) {
                            float xv = (i == 0) ? xa0[j + f + 1] : xa1[j + f + 1];
                            a0 = fmaf(wl[(0 * CIc + i) * Sc + s3][f], xv, a0);
                            a1 = fmaf(wl[(1 * CIc + i) * Sc + s3][f], xv, a1);
                        }
                    }
                    acc[0][j] = a0;
                    acc[1][j] = a1;
                }
            }
        }

        // store: 2 nontemporal dwordx4 per tile (NT proven right: r13 plain stores -7.3us)
        float* ob = out + (size_t)bdk * COc * Lc + gl0;
        f32x4 v0 = { acc[0][0], acc[0][1], acc[0][2], acc[0][3] };
        f32x4 v1 = { acc[1][0], acc[1][1], acc[1][2], acc[1][3] };
        __builtin_nontemporal_store(v0, (f32x4*)(ob));
        __builtin_nontemporal_store(v1, (f32x4*)(ob + Lc));
    }
}

extern "C" void kernel_launch(void* const* d_in, const int* in_sizes, int n_in,
                              void* d_out, int out_size, void* d_ws, size_t ws_size,
                              hipStream_t stream) {
    const float* x    = (const float*)d_in[0];
    const float* w    = (const float*)d_in[1];
    const float* bias = (const float*)d_in[2];
    float* out        = (float*)d_out;

    // 1024 blocks = full-grid resident (4 blocks/CU by LDS), staggered barrier release
    cde_bcr_kernel<<<dim3(Bc * Dc * Kc), NTHREADS, 0, stream>>>(x, w, bias, out);
}